// Round 7
// baseline (6069.041 us; speedup 1.0000x reference)
//
#include <hip/hip_runtime.h>
#include <hip/hip_bf16.h>
#include <cmath>

// ---------------------------------------------------------------------------
// Decoder: 27 greedy steps of attention + LSTM + vocab argmax, all f32.
// Dims fixed by the problem: B=64, T=512, H=512, E=512, V=50257, steps=27.
// ---------------------------------------------------------------------------

#define TKK 16

// Generic C[M x N] = A[M x K] * B[N x K]^T tile GEMM.
// Tile 64(m) x 128(n), 256 threads, thread computes 4x8.
// grid = (N/128, M/64, ksplit). Each z consumes Kchunk columns starting at
// z*Kchunk and writes to C + z*c_zstride (partials when ksplit>1).
__global__ __launch_bounds__(256) void gemm_tile(
    const float* __restrict__ A, int lda,
    const float* __restrict__ B, int ldb,
    float* __restrict__ C, int ldc,
    int Kchunk, long long c_zstride)
{
  __shared__ __align__(16) float At[TKK][68];   // [kk][m], padded
  __shared__ __align__(16) float Bt[TKK][132];  // [kk][n], padded
  const int tid = threadIdx.x;
  const int tx = tid & 15, ty = tid >> 4;
  const long long mbase = (long long)blockIdx.y * 64;
  const long long nbase = (long long)blockIdx.x * 128;
  const int kbase = blockIdx.z * Kchunk;
  const float* Ap = A + mbase * lda + kbase;
  const float* Bp = B + nbase * ldb + kbase;
  float acc[4][8];
#pragma unroll
  for (int i = 0; i < 4; i++)
#pragma unroll
    for (int j = 0; j < 8; j++) acc[i][j] = 0.f;

  const int lm = tid >> 2;         // 0..63
  const int lk = (tid & 3) << 2;   // 0,4,8,12
  for (int k0 = 0; k0 < Kchunk; k0 += TKK) {
    float4 av = *(const float4*)(Ap + (long long)lm * lda + k0 + lk);
    At[lk + 0][lm] = av.x; At[lk + 1][lm] = av.y;
    At[lk + 2][lm] = av.z; At[lk + 3][lm] = av.w;
#pragma unroll
    for (int r = 0; r < 2; r++) {
      int n = (tid + r * 256) >> 2;  // 0..127
      float4 bv = *(const float4*)(Bp + (long long)n * ldb + k0 + lk);
      Bt[lk + 0][n] = bv.x; Bt[lk + 1][n] = bv.y;
      Bt[lk + 2][n] = bv.z; Bt[lk + 3][n] = bv.w;
    }
    __syncthreads();
#pragma unroll
    for (int kk = 0; kk < TKK; ++kk) {
      float4 a4 = *(const float4*)&At[kk][ty * 4];
      float4 b0 = *(const float4*)&Bt[kk][tx * 8];
      float4 b1 = *(const float4*)&Bt[kk][tx * 8 + 4];
      float as[4] = {a4.x, a4.y, a4.z, a4.w};
      float bs[8] = {b0.x, b0.y, b0.z, b0.w, b1.x, b1.y, b1.z, b1.w};
#pragma unroll
      for (int i = 0; i < 4; i++)
#pragma unroll
        for (int j = 0; j < 8; j++)
          acc[i][j] = fmaf(as[i], bs[j], acc[i][j]);
    }
    __syncthreads();
  }
  float* Cp = C + (long long)blockIdx.z * c_zstride;
#pragma unroll
  for (int i = 0; i < 4; i++) {
    long long m = mbase + ty * 4 + i;
#pragma unroll
    for (int j = 0; j < 8; j += 4) {
      float4 v;
      v.x = acc[i][j]; v.y = acc[i][j + 1]; v.z = acc[i][j + 2]; v.w = acc[i][j + 3];
      *(float4*)(Cp + m * ldc + nbase + tx * 8 + j) = v;
    }
  }
}

// Build Wcat[2048][1536] = [W_ih(1024 cols) | W_hh(512 cols)] once per launch.
__global__ __launch_bounds__(256) void wcat_kernel(
    const float* __restrict__ W_ih, const float* __restrict__ W_hh,
    float* __restrict__ wcat)
{
  long long fi = (long long)blockIdx.x * 256 + threadIdx.x;  // float4 index
  if (fi >= 2048LL * 1536 / 4) return;
  int k = (int)(fi / 384);
  int c = (int)(fi % 384) * 4;
  float4 v;
  if (c < 1024) v = *(const float4*)(W_ih + (long long)k * 1024 + c);
  else          v = *(const float4*)(W_hh + (long long)k * 512 + (c - 1024));
  *(float4*)(wcat + fi * 4) = v;
}

// h = h0[0], c = c0[0], y = bos
__global__ __launch_bounds__(256) void init_kernel(
    const float* __restrict__ h0, const float* __restrict__ c0,
    const int* __restrict__ bos,
    float* __restrict__ h, float* __restrict__ c, int* __restrict__ y)
{
  int i = blockIdx.x * 256 + threadIdx.x;
  if (i < 64 * 512) { h[i] = h0[i]; c[i] = c0[i]; }
  if (i < 64) y[i] = bos[0];
}

// scores[b][t] = mask ? sum_h v[h]*tanh(whenc[b][t][h] + s[b][h]) : -1e9
// grid (B=64, T/128=4), 256 threads = 4 waves x 32 t each.
__global__ __launch_bounds__(256) void scores_kernel(
    const float* __restrict__ whenc,   // [B][T][H]
    const float* __restrict__ spart,   // [4][B][H] partials of h@W_s^T
    const float* __restrict__ vvec,    // [H]
    const int* __restrict__ mask,      // [B][T]
    float* __restrict__ scores)        // [B][T]
{
  const int b = blockIdx.x, tc = blockIdx.y, tid = threadIdx.x;
  __shared__ __align__(16) float sS[512];
  __shared__ __align__(16) float sV[512];
  for (int i = tid; i < 512; i += 256) {
    sS[i] = spart[0 * 64 * 512 + b * 512 + i] + spart[1 * 64 * 512 + b * 512 + i]
          + spart[2 * 64 * 512 + b * 512 + i] + spart[3 * 64 * 512 + b * 512 + i];
    sV[i] = vvec[i];
  }
  __syncthreads();
  const int wave = tid >> 6, lane = tid & 63;
  const int t0 = tc * 128 + wave * 32;
  for (int tt = 0; tt < 32; ++tt) {
    int t = t0 + tt;
    const float* row = whenc + ((long long)b * 512 + t) * 512;
    float p = 0.f;
#pragma unroll
    for (int u = 0; u < 2; ++u) {
      int hb = u * 256 + lane * 4;
      float4 w = *(const float4*)(row + hb);
      float4 s4 = *(const float4*)&sS[hb];
      float4 v4 = *(const float4*)&sV[hb];
      p = fmaf(v4.x, tanhf(w.x + s4.x), p);
      p = fmaf(v4.y, tanhf(w.y + s4.y), p);
      p = fmaf(v4.z, tanhf(w.z + s4.z), p);
      p = fmaf(v4.w, tanhf(w.w + s4.w), p);
    }
#pragma unroll
    for (int off = 32; off; off >>= 1) p += __shfl_xor(p, off);
    if (lane == 0)
      scores[b * 512 + t] = mask[b * 512 + t] ? p : -1e9f;
  }
}

// softmax over T (recomputed per block) + ctx partial over a 128-t chunk.
// grid (B=64, 4), 256 threads; thread owns h = 2*tid, 2*tid+1.
__global__ __launch_bounds__(256) void ctx_kernel(
    const float* __restrict__ scores,  // [B][T] (masked)
    const float* __restrict__ enc,     // [B][T][H]
    float* __restrict__ ctxp)          // [B][4][H]
{
  const int b = blockIdx.x, tc = blockIdx.y, tid = threadIdx.x;
  __shared__ float sc[512];
  __shared__ float red[256];
  float l0 = scores[b * 512 + tid];
  float l1 = scores[b * 512 + 256 + tid];
  red[tid] = fmaxf(l0, l1);
  __syncthreads();
  for (int s = 128; s > 0; s >>= 1) {
    if (tid < s) red[tid] = fmaxf(red[tid], red[tid + s]);
    __syncthreads();
  }
  float mx = red[0];
  __syncthreads();
  float e0 = expf(l0 - mx), e1 = expf(l1 - mx);
  sc[tid] = e0; sc[tid + 256] = e1;
  red[tid] = e0 + e1;
  __syncthreads();
  for (int s = 128; s > 0; s >>= 1) {
    if (tid < s) red[tid] += red[tid + s];
    __syncthreads();
  }
  float inv = 1.f / red[0];
  float a0 = 0.f, a1 = 0.f;
  for (int u = 0; u < 128; ++u) {
    int t = tc * 128 + u;
    float w = sc[t] * inv;
    const float* row = enc + ((long long)b * 512 + t) * 512;
    float2 e = *(const float2*)(row + tid * 2);
    a0 = fmaf(w, e.x, a0);
    a1 = fmaf(w, e.y, a1);
  }
  float2 o; o.x = a0; o.y = a1;
  *(float2*)(ctxp + ((long long)(b * 4 + tc)) * 512 + tid * 2) = o;
}

// x[b][0:512]=emb[y[b]], [512:1024]=sum ctx partials, [1024:1536]=h[b]
__global__ __launch_bounds__(256) void xbuild_kernel(
    const float* __restrict__ emb, const int* __restrict__ y,
    const float* __restrict__ ctxp, const float* __restrict__ h,
    float* __restrict__ x)
{
  const int b = blockIdx.x, tid = threadIdx.x;
  const int yb = y[b];
  for (int i = tid; i < 1536; i += 256) {
    float val;
    if (i < 512) {
      val = emb[(long long)yb * 512 + i];
    } else if (i < 1024) {
      int hh = i - 512;
      val = ctxp[(b * 4 + 0) * 512 + hh] + ctxp[(b * 4 + 1) * 512 + hh]
          + ctxp[(b * 4 + 2) * 512 + hh] + ctxp[(b * 4 + 3) * 512 + hh];
    } else {
      val = h[b * 512 + (i - 1024)];
    }
    x[b * 1536 + i] = val;
  }
}

// combine gate partials + biases, LSTM cell update (in-place h, c).
__global__ __launch_bounds__(512) void lstm_kernel(
    const float* __restrict__ gpart,  // [3][B][2048]
    const float* __restrict__ b_ih, const float* __restrict__ b_hh,
    float* __restrict__ h, float* __restrict__ c)
{
  const int b = blockIdx.x, hc = threadIdx.x;
  float g[4];
#pragma unroll
  for (int q = 0; q < 4; q++) {
    int k = q * 512 + hc;
    float s = b_ih[k] + b_hh[k];
    s += gpart[(0 * 64 + b) * 2048 + k];
    s += gpart[(1 * 64 + b) * 2048 + k];
    s += gpart[(2 * 64 + b) * 2048 + k];
    g[q] = s;
  }
  float ig = 1.f / (1.f + expf(-g[0]));
  float fg = 1.f / (1.f + expf(-g[1]));
  float gg = tanhf(g[2]);
  float og = 1.f / (1.f + expf(-g[3]));
  float c2 = fg * c[b * 512 + hc] + ig * gg;
  float h2 = og * tanhf(c2);
  c[b * 512 + hc] = c2;
  h[b * 512 + hc] = h2;
}

// logits tile (64 x 128) + bias + per-block per-b argmax partial.
// grid (ceil(V/128)), 256 threads.
__global__ __launch_bounds__(256) void logits_kernel(
    const float* __restrict__ A,     // h2 [64][512]
    const float* __restrict__ W,     // [V][512]
    const float* __restrict__ bias,  // [V]
    int V, float* __restrict__ pval, int* __restrict__ pidx, int nvc)
{
  __shared__ __align__(16) float At[TKK][68];
  __shared__ __align__(16) float Bt[TKK][132];
  __shared__ float lv[64][16];
  __shared__ int   li[64][16];
  const int tid = threadIdx.x;
  const int tx = tid & 15, ty = tid >> 4;
  const int nbase = blockIdx.x * 128;
  float acc[4][8];
#pragma unroll
  for (int i = 0; i < 4; i++)
#pragma unroll
    for (int j = 0; j < 8; j++) acc[i][j] = 0.f;
  const int lm = tid >> 2;
  const int lk = (tid & 3) << 2;
  for (int k0 = 0; k0 < 512; k0 += TKK) {
    float4 av = *(const float4*)(A + lm * 512 + k0 + lk);
    At[lk + 0][lm] = av.x; At[lk + 1][lm] = av.y;
    At[lk + 2][lm] = av.z; At[lk + 3][lm] = av.w;
#pragma unroll
    for (int r = 0; r < 2; r++) {
      int n = (tid + r * 256) >> 2;
      int ng = nbase + n;
      float4 bv = make_float4(0.f, 0.f, 0.f, 0.f);
      if (ng < V) bv = *(const float4*)(W + (long long)ng * 512 + k0 + lk);
      Bt[lk + 0][n] = bv.x; Bt[lk + 1][n] = bv.y;
      Bt[lk + 2][n] = bv.z; Bt[lk + 3][n] = bv.w;
    }
    __syncthreads();
#pragma unroll
    for (int kk = 0; kk < TKK; ++kk) {
      float4 a4 = *(const float4*)&At[kk][ty * 4];
      float4 b0 = *(const float4*)&Bt[kk][tx * 8];
      float4 b1 = *(const float4*)&Bt[kk][tx * 8 + 4];
      float as[4] = {a4.x, a4.y, a4.z, a4.w};
      float bs[8] = {b0.x, b0.y, b0.z, b0.w, b1.x, b1.y, b1.z, b1.w};
#pragma unroll
      for (int i = 0; i < 4; i++)
#pragma unroll
        for (int j = 0; j < 8; j++)
          acc[i][j] = fmaf(as[i], bs[j], acc[i][j]);
    }
    __syncthreads();
  }
  // per-thread argmax over its 8 v's, tie -> lowest index (scan ascending)
#pragma unroll
  for (int i = 0; i < 4; i++) {
    float bv_ = -INFINITY; int bi_ = 0x7fffffff;
#pragma unroll
    for (int j = 0; j < 8; j++) {
      int vg = nbase + tx * 8 + j;
      if (vg < V) {
        float val = acc[i][j] + bias[vg];
        if (val > bv_) { bv_ = val; bi_ = vg; }
      }
    }
    lv[ty * 4 + i][tx] = bv_; li[ty * 4 + i][tx] = bi_;
  }
  __syncthreads();
  if (tid < 64) {
    float bv_ = -INFINITY; int bi_ = 0x7fffffff;
#pragma unroll
    for (int t = 0; t < 16; t++) {      // ascending tx = ascending v
      if (lv[tid][t] > bv_) { bv_ = lv[tid][t]; bi_ = li[tid][t]; }
    }
    pval[tid * nvc + blockIdx.x] = bv_;
    pidx[tid * nvc + blockIdx.x] = bi_;
  }
}

// final argmax over nvc partials per b; writes next y and the output token.
__global__ __launch_bounds__(64) void argfinal_kernel(
    const float* __restrict__ pval, const int* __restrict__ pidx, int nvc,
    int* __restrict__ y, int* __restrict__ out, int step, int steps)
{
  const int b = blockIdx.x, lane = threadIdx.x;
  float bv = -INFINITY; int bi = 0x7fffffff;
  for (int ci = lane; ci < nvc; ci += 64) {
    float v = pval[b * nvc + ci];
    int ix = pidx[b * nvc + ci];
    if (v > bv || (v == bv && ix < bi)) { bv = v; bi = ix; }
  }
#pragma unroll
  for (int off = 32; off; off >>= 1) {
    float ov = __shfl_xor(bv, off);
    int oi = __shfl_xor(bi, off);
    if (ov > bv || (ov == bv && oi < bi)) { bv = ov; bi = oi; }
  }
  if (lane == 0) { y[b] = bi; out[b * steps + step] = bi; }
}

extern "C" void kernel_launch(void* const* d_in, const int* in_sizes, int n_in,
                              void* d_out, int out_size, void* d_ws, size_t ws_size,
                              hipStream_t stream) {
  const float* enc_seq = (const float*)d_in[0];   // [64][512][512]
  const int*   enc_mask = (const int*)d_in[1];    // [64][512]
  const float* h0 = (const float*)d_in[2];        // [1][64][512]
  const float* c0 = (const float*)d_in[3];
  const int*   bos = (const int*)d_in[4];
  const float* emb = (const float*)d_in[7];       // [V][512]
  const float* W_h = (const float*)d_in[8];       // [512][512]
  const float* W_s = (const float*)d_in[9];
  const float* vvec = (const float*)d_in[10];     // [512]
  const float* W_ih = (const float*)d_in[11];     // [2048][1024]
  const float* W_hh = (const float*)d_in[12];     // [2048][512]
  const float* b_ih = (const float*)d_in[13];
  const float* b_hh = (const float*)d_in[14];
  const float* W_out = (const float*)d_in[15];    // [V][512]
  const float* b_out = (const float*)d_in[16];

  const int B = 64, T = 512, H = 512;
  const int V = in_sizes[16];                     // 50257
  const int steps = out_size / B;                 // 27
  const int NVC = (V + 127) / 128;                // 393
  int* out = (int*)d_out;

  // workspace layout (floats), 16-float aligned chunks
  float* ws = (float*)d_ws;
  size_t off = 0;
  auto alloc = [&](size_t n) { float* p = ws + off; off += (n + 15) & ~(size_t)15; return p; };
  float* whenc  = alloc((size_t)B * T * H);       // 16.8M
  float* scores = alloc((size_t)B * T);
  float* spart  = alloc(4ull * B * H);
  float* ctxp   = alloc((size_t)B * 4 * H);
  float* xbuf   = alloc((size_t)B * 1536);
  float* gpart  = alloc(3ull * B * 2048);
  float* wcat   = alloc(2048ull * 1536);
  float* hbuf   = alloc((size_t)B * H);
  float* cbuf   = alloc((size_t)B * H);
  float* pval   = alloc((size_t)B * NVC);
  int*   ybuf   = (int*)alloc(B);
  int*   pidx   = (int*)alloc((size_t)B * NVC);
  (void)ws_size;

  init_kernel<<<128, 256, 0, stream>>>(h0, c0, bos, hbuf, cbuf, ybuf);
  wcat_kernel<<<3072, 256, 0, stream>>>(W_ih, W_hh, wcat);

  // Wh_enc = enc_seq(32768x512) @ W_h^T -> [32768][512]
  gemm_tile<<<dim3(4, 512, 1), 256, 0, stream>>>(
      enc_seq, 512, W_h, 512, whenc, 512, 512, 0);

  for (int step = 0; step < steps; ++step) {
    // s partials: h(64x512) @ W_s^T, K split 4 -> spart[4][64][512]
    gemm_tile<<<dim3(4, 1, 4), 256, 0, stream>>>(
        hbuf, 512, W_s, 512, spart, 512, 128, (long long)B * H);
    scores_kernel<<<dim3(64, 4), 256, 0, stream>>>(whenc, spart, vvec, enc_mask, scores);
    ctx_kernel<<<dim3(64, 4), 256, 0, stream>>>(scores, enc_seq, ctxp);
    xbuild_kernel<<<64, 256, 0, stream>>>(emb, ybuf, ctxp, hbuf, xbuf);
    // gates partials: x(64x1536) @ Wcat^T(2048x1536), K split 3 -> gpart[3][64][2048]
    gemm_tile<<<dim3(16, 1, 3), 256, 0, stream>>>(
        xbuf, 1536, wcat, 1536, gpart, 2048, 512, (long long)B * 2048);
    lstm_kernel<<<64, 512, 0, stream>>>(gpart, b_ih, b_hh, hbuf, cbuf);
    logits_kernel<<<NVC, 256, 0, stream>>>(hbuf, W_out, b_out, V, pval, pidx, NVC);
    argfinal_kernel<<<64, 64, 0, stream>>>(pval, pidx, NVC, ybuf, out, step, steps);
  }
}